// Round 10
// baseline (1779.051 us; speedup 1.0000x reference)
//
#include <hip/hip_runtime.h>

// GatedSpatialLinearAttention on MI355X (gfx950). Round 7 kernel (4th submit; never ran).
// Split-bf16 (hi+lo) 3-pass MFMA emulation of fp32 GEMMs throughout.
// R7: k_smq fused into k_att (k_smatt): qf f32 staged per block, softmax-h in
// LDS, frags built in-place -> qT round-trip (512MB) eliminated. g now
// pixel-major f32 (vectorized gate reads). k_proj BK=32 -> 36KB LDS, 4 blk/CU.

typedef unsigned short u16;
typedef unsigned int u32;
typedef __bf16 bf16x8 __attribute__((ext_vector_type(8)));
typedef float f32x4 __attribute__((ext_vector_type(4)));

typedef const __attribute__((address_space(1))) void* gas_t;
typedef __attribute__((address_space(3))) void* las_t;
__device__ __forceinline__ void gll16(const void* g, void* l) {
    __builtin_amdgcn_global_load_lds((gas_t)g, (las_t)l, 16, 0, 0);
}

__device__ inline float bf2f(u16 v) { union { u32 i; float f; } u; u.i = ((u32)v) << 16; return u.f; }
__device__ inline u16 f2bf(float f) {
    union { float f; u32 i; } u; u.f = f;
    u32 r = (u.i + 0x7fffu + ((u.i >> 16) & 1u)) >> 16;   // RNE
    return (u16)r;
}
__device__ inline void split2(float v, u16& h, u16& l) {
    h = f2bf(v);
    l = f2bf(v - bf2f(h));
}

// ------------------------------------------------- cvt weights to hi/lo pairs
__global__ void k_cvt_w(const float* __restrict__ Wq, const float* __restrict__ Wk,
                        const float* __restrict__ Wv, const float* __restrict__ Wg,
                        const float* __restrict__ Wo,
                        u16* __restrict__ Wh, u16* __restrict__ Wl,
                        u16* __restrict__ Woh, u16* __restrict__ Wol)
{
    int idx = blockIdx.x * 256 + threadIdx.x;
    if (idx < 524288) {                       // W_all[2048][256] = [q;k;v;g]
        int o = idx >> 8, c = idx & 255;
        int which = o >> 9, r = o & 511;
        const float* s = (which == 0) ? Wq : (which == 1) ? Wk : (which == 2) ? Wv : Wg;
        u16 h, l; split2(s[r * 256 + c], h, l);
        Wh[idx] = h; Wl[idx] = l;
    } else {
        int j = idx - 524288;                 // Wo[256][512]
        if (j < 131072) { u16 h, l; split2(Wo[j], h, l); Woh[j] = h; Wol[j] = l; }
    }
}

// ----------------------- cvt x -> xh/xl [bf_local][n][c] bf16 pairs (chunked)
__global__ __launch_bounds__(256) void k_cvt_x(const float* __restrict__ x,
                                               u16* __restrict__ xh, u16* __restrict__ xl,
                                               int c0)
{
    __shared__ __align__(16) u16 tileh[64 * 132];
    __shared__ __align__(16) u16 tilel[64 * 132];
    const int t = threadIdx.x;
    const int bfl = blockIdx.y;
    const int bfg = c0 + bfl;
    const int n0 = blockIdx.x * 128;
    const int b_ = bfg >> 4, f_ = bfg & 15;
    for (int s = 0; s < 2; ++s) {
        for (int ch2 = 0; ch2 < 2; ++ch2) {
            __syncthreads();
            for (int p = 0; p < 8; ++p) {
                int cl = p * 16 + (t >> 4);
                int c = ch2 * 128 + cl;
                const float* sp = x + (((size_t)b_ * 256 + c) * 16 + f_) * 4096
                                    + n0 + s * 64 + (t & 15) * 4;
                float4 v = *(const float4*)sp;
                float vv[4] = { v.x, v.y, v.z, v.w };
#pragma unroll
                for (int j = 0; j < 4; ++j) {
                    int nl = (t & 15) * 4 + j;
                    u16 h, l; split2(vv[j], h, l);
                    tileh[nl * 132 + cl] = h;
                    tilel[nl * 132 + cl] = l;
                }
            }
            __syncthreads();
#pragma unroll
            for (int i = 0; i < 4; ++i) {
                int flat = t + i * 256;
                int nn = flat >> 4, cc = flat & 15;
                size_t off = ((size_t)bfl * 4096 + n0 + s * 64 + nn) * 256 + ch2 * 128 + cc * 8;
                *(uint4*)(xh + off) = *(const uint4*)(tileh + nn * 132 + cc * 8);
                *(uint4*)(xl + off) = *(const uint4*)(tilel + nn * 132 + cc * 8);
            }
        }
    }
}

// ---------------------------------------- fused projection (single dispatch)
// my 0-3: q -> qf f32 [n][512] pixel-major; 4-7: k softmax-w -> kh/kl;
// 8-11: v -> vh/vl; 12-15: g -> gf f32 [n][512] pixel-major sigmoid(+bg).
// BK=32: staging 32KB, smem 36352B -> 4 blocks/CU.
__global__ __launch_bounds__(256) void k_proj(
    const u16* __restrict__ Wh, const u16* __restrict__ Wl,
    const u16* __restrict__ xh, const u16* __restrict__ xl,
    const float* __restrict__ bg,
    float* __restrict__ qf,
    u16* __restrict__ kh, u16* __restrict__ kl,
    u16* __restrict__ vh, u16* __restrict__ vl,
    float* __restrict__ gf)
{
    __shared__ __align__(16) char smem[36352];
    u16* Ah = (u16*)smem;                 // [128][32] each; LDS linear,
    u16* Al = (u16*)(smem + 8192);        // source pre-swizzled (c^((row>>1)&3))
    u16* Bh = (u16*)(smem + 16384);
    u16* Bl = (u16*)(smem + 24576);
    float* Csh = (float*)smem;            // [128][69] f32 (35328B), reused
    const int t = threadIdx.x;
    const int bfl = blockIdx.z;
    const int by = blockIdx.y;
    const int m0 = (by < 4) ? by * 128 : 512 + (by - 4) * 128;
    const int n0 = blockIdx.x * 128;
    const int lane = t & 63, wv = t >> 6, wm = wv >> 1, wn = wv & 1;
    f32x4 acc[4][4] = {};
    const u16* Aph = Wh + (size_t)m0 * 256;
    const u16* Apl = Wl + (size_t)m0 * 256;
    const u16* Bph = xh + ((size_t)bfl * 4096 + n0) * 256;
    const u16* Bpl = xl + ((size_t)bfl * 4096 + n0) * 256;

    for (int kt = 0; kt < 8; ++kt) {
        const int k0 = kt * 32;
#pragma unroll
        for (int jj = 0; jj < 2; ++jj) {      // 1KB seg = 16 rows x 64B
            int s = wv * 2 + jj;
            int row = s * 16 + (lane >> 2);
            int csrc = (lane & 3) ^ ((row >> 1) & 3);
            size_t go = (size_t)row * 256 + k0 + csrc * 8;
            gll16(Aph + go, Ah + s * 512);
            gll16(Apl + go, Al + s * 512);
            gll16(Bph + go, Bh + s * 512);
            gll16(Bpl + go, Bl + s * 512);
        }
        __syncthreads();
        bf16x8 afh[4], afl[4], bfh[4], bfl_[4];
#pragma unroll
        for (int i = 0; i < 4; ++i) {
            int ra = wm * 64 + i * 16 + (lane & 15);
            int ca = ((lane >> 4) ^ ((ra >> 1) & 3)) * 8;
            afh[i] = *(const bf16x8*)(Ah + ra * 32 + ca);
            afl[i] = *(const bf16x8*)(Al + ra * 32 + ca);
            int rb = wn * 64 + i * 16 + (lane & 15);
            int cb = ((lane >> 4) ^ ((rb >> 1) & 3)) * 8;
            bfh[i] = *(const bf16x8*)(Bh + rb * 32 + cb);
            bfl_[i] = *(const bf16x8*)(Bl + rb * 32 + cb);
        }
#pragma unroll
        for (int mi = 0; mi < 4; ++mi)
#pragma unroll
            for (int ni = 0; ni < 4; ++ni) {
                acc[mi][ni] = __builtin_amdgcn_mfma_f32_16x16x32_bf16(afh[mi], bfh[ni], acc[mi][ni], 0, 0, 0);
                acc[mi][ni] = __builtin_amdgcn_mfma_f32_16x16x32_bf16(afh[mi], bfl_[ni], acc[mi][ni], 0, 0, 0);
                acc[mi][ni] = __builtin_amdgcn_mfma_f32_16x16x32_bf16(afl[mi], bfh[ni], acc[mi][ni], 0, 0, 0);
            }
        __syncthreads();
    }

    const int sector = m0 >> 9;               // 0:q 1:k 2:v 3:g
    for (int ph = 0; ph < 2; ++ph) {
        if (wn == ph) {
#pragma unroll
            for (int mi = 0; mi < 4; ++mi)
#pragma unroll
                for (int ni = 0; ni < 4; ++ni)
#pragma unroll
                    for (int r = 0; r < 4; ++r) {
                        int gr = wm * 64 + mi * 16 + (lane >> 4) * 4 + r;
                        int gcl = ni * 16 + (lane & 15);
                        Csh[gr * 69 + gcl] = acc[mi][ni][r];
                    }
        }
        __syncthreads();
        if (sector == 0 || sector == 3) {     // pixel-major f32 [n][512]
            float* dstbuf = (sector == 0) ? qf : gf;
            const int cbase = m0 & 511;
#pragma unroll
            for (int rr = 0; rr < 2; ++rr) {
                int n_loc = rr * 32 + (t >> 3);
                int oc = t & 7;
                float* dst = dstbuf + ((size_t)bfl * 4096 + n0 + ph * 64 + n_loc) * 512 + cbase;
#pragma unroll
                for (int j = 0; j < 4; ++j) {
                    f32x4 o;
#pragma unroll
                    for (int c = 0; c < 4; ++c) {
                        float v = Csh[(j * 32 + oc * 4 + c) * 69 + n_loc];
                        if (sector == 3)
                            v = 1.0f / (1.0f + expf(-(v + bg[cbase + j * 32 + oc * 4 + c])));
                        o[c] = v;
                    }
                    *(f32x4*)(dst + j * 32 + oc * 4) = o;
                }
            }
        } else if (t < 128) {
            const float* src = Csh + t * 69;
            const int oloc = (m0 & 511) + t;
            const size_t doff = ((size_t)bfl * 512 + oloc) * 4096 + n0 + ph * 64;
            if (sector == 2) {                // v split pair
#pragma unroll
                for (int i = 0; i < 8; ++i) {
                    union { u16 h[8]; uint4 u; } ph_, pl_;
#pragma unroll
                    for (int j = 0; j < 8; ++j) split2(src[i * 8 + j], ph_.h[j], pl_.h[j]);
                    *(uint4*)(vh + doff + i * 8) = ph_.u;
                    *(uint4*)(vl + doff + i * 8) = pl_.u;
                }
            } else {                          // k: softmax over the 64-px w row
                float mx = -3.0e38f;
                for (int j = 0; j < 64; ++j) mx = fmaxf(mx, src[j]);
                float sum = 0.f;
                for (int j = 0; j < 64; ++j) sum += expf(src[j] - mx);
                float rs = 1.0f / sum;
#pragma unroll
                for (int i = 0; i < 8; ++i) {
                    union { u16 h[8]; uint4 u; } ph_, pl_;
#pragma unroll
                    for (int j = 0; j < 8; ++j) {
                        float p = expf(src[i * 8 + j] - mx) * rs;
                        split2(p, ph_.h[j], pl_.h[j]);
                    }
                    *(uint4*)(kh + doff + i * 8) = ph_.u;
                    *(uint4*)(kl + doff + i * 8) = pl_.u;
                }
            }
        }
        __syncthreads();
    }
}

// ---- per (octant, bh): kv,vsum,ksum partials over 512 px (ones-row trick)
__global__ __launch_bounds__(256) void k_kv(
    const u16* __restrict__ kh, const u16* __restrict__ kl,
    const u16* __restrict__ vh, const u16* __restrict__ vl,
    float* __restrict__ kvp, float* __restrict__ vsp, float* __restrict__ ksp)
{
    __shared__ __align__(16) char smem[65536];
    u16* Kh = (u16*)smem;
    u16* Kl = (u16*)(smem + 16384);
    u16* Vh = (u16*)(smem + 32768);
    u16* Vl = (u16*)(smem + 49152);
    float* mrg = (float*)smem;
    const int t = threadIdx.x;
    const int oct = blockIdx.x;
    const int bh = blockIdx.y;
    const int NBH = gridDim.y;
    const int lane = t & 63, wv = t >> 6;
    const size_t hb = (size_t)bh * 64 * 4096;

    f32x4 acc[5][5] = {};
    bf16x8 ones;
#pragma unroll
    for (int j = 0; j < 8; ++j) ones[j] = (lane & 15) == 0 ? (__bf16)1.0f : (__bf16)0.0f;

    for (int cc = 0; cc < 4; ++cc) {
        const int pxc = oct * 512 + cc * 128;
#pragma unroll
        for (int jj = 0; jj < 4; ++jj) {
            int s = wv * 4 + jj;
            int row = s * 4 + (lane >> 4);
            int csrc = (lane & 15) ^ (row & 7);
            size_t go = hb + (size_t)row * 4096 + pxc + csrc * 8;
            gll16(kh + go, Kh + s * 512);
            gll16(kl + go, Kl + s * 512);
            gll16(vh + go, Vh + s * 512);
            gll16(vl + go, Vl + s * 512);
        }
        __syncthreads();
        bf16x8 ah[4], al[4], bh_[4], bl_[4];
#pragma unroll
        for (int i = 0; i < 4; ++i) {
            int ra = i * 16 + (lane & 15);
            int kc = (wv * 4 + (lane >> 4)) ^ (ra & 7);
            int off = ra * 128 + kc * 8;
            ah[i]  = *(const bf16x8*)(Kh + off);
            al[i]  = *(const bf16x8*)(Kl + off);
            bh_[i] = *(const bf16x8*)(Vh + off);
            bl_[i] = *(const bf16x8*)(Vl + off);
        }
#pragma unroll
        for (int di = 0; di < 5; ++di) {
            bf16x8 a = (di < 4) ? ah[di] : ones;
#pragma unroll
            for (int ei = 0; ei < 5; ++ei) {
                bf16x8 b = (ei < 4) ? bh_[ei] : ones;
                acc[di][ei] = __builtin_amdgcn_mfma_f32_16x16x32_bf16(a, b, acc[di][ei], 0, 0, 0);
            }
        }
#pragma unroll
        for (int di = 0; di < 5; ++di) {
            bf16x8 a = (di < 4) ? ah[di] : ones;
#pragma unroll
            for (int ei = 0; ei < 4; ++ei)
                acc[di][ei] = __builtin_amdgcn_mfma_f32_16x16x32_bf16(a, bl_[ei], acc[di][ei], 0, 0, 0);
        }
#pragma unroll
        for (int di = 0; di < 4; ++di)
#pragma unroll
            for (int ei = 0; ei < 5; ++ei) {
                bf16x8 b = (ei < 4) ? bh_[ei] : ones;
                acc[di][ei] = __builtin_amdgcn_mfma_f32_16x16x32_bf16(al[di], b, acc[di][ei], 0, 0, 0);
            }
        __syncthreads();
    }

    float* kvm = mrg;
    float* vsm = mrg + 64 * 68;
    float* ksm = mrg + 64 * 68 + 64;
    for (int i = t; i < 64 * 68 + 128; i += 256) mrg[i] = 0.f;
    __syncthreads();
#pragma unroll
    for (int di = 0; di < 4; ++di)
#pragma unroll
        for (int ei = 0; ei < 4; ++ei)
#pragma unroll
            for (int r = 0; r < 4; ++r) {
                int d = di * 16 + (lane >> 4) * 4 + r;
                int e = ei * 16 + (lane & 15);
                atomicAdd(&kvm[d * 68 + e], acc[di][ei][r]);
            }
    if (lane < 16) {
#pragma unroll
        for (int ei = 0; ei < 4; ++ei) atomicAdd(&vsm[ei * 16 + lane], acc[4][ei][0]);
    }
    if ((lane & 15) == 0) {
#pragma unroll
        for (int di = 0; di < 4; ++di)
#pragma unroll
            for (int r = 0; r < 4; ++r)
                atomicAdd(&ksm[di * 16 + (lane >> 4) * 4 + r], acc[di][4][r]);
    }
    __syncthreads();
    float* op = kvp + ((size_t)oct * NBH + bh) * 4096;
#pragma unroll
    for (int i = 0; i < 16; ++i) {
        int idx = t + i * 256;
        op[idx] = kvm[(idx >> 6) * 68 + (idx & 63)];
    }
    if (t < 64) {
        vsp[((size_t)oct * NBH + bh) * 64 + t] = vsm[t];
        ksp[((size_t)oct * NBH + bh) * 64 + t] = 512.0f + ksm[t];
    }
}

// --- merge octants -> kvT_aug [bh][80 m][64 k] hi/lo (row64=ksl) + aux(csl,kstp)
__global__ __launch_bounds__(256) void k_merge(
    const float* __restrict__ kvp, const float* __restrict__ vsp,
    const float* __restrict__ ksp,
    u16* __restrict__ kvTh, u16* __restrict__ kvTl,
    float* __restrict__ aux, int NBH)
{
    __shared__ float kv[64 * 68];
    __shared__ float vsl[64];
    __shared__ float kslL[64];
    const int t = threadIdx.x;
    const int bh = blockIdx.x;
#pragma unroll
    for (int i = 0; i < 16; ++i) {
        int idx = t + i * 256;
        float s = 0.f;
#pragma unroll
        for (int o = 0; o < 8; ++o) s += kvp[((size_t)o * NBH + bh) * 4096 + idx];
        kv[(idx >> 6) * 68 + (idx & 63)] = s;
    }
    if (t < 64) {
        float a = 0.f, b = 0.f;
#pragma unroll
        for (int o = 0; o < 8; ++o) {
            a += vsp[((size_t)o * NBH + bh) * 64 + t];
            b += ksp[((size_t)o * NBH + bh) * 64 + t];
        }
        vsl[t] = a; kslL[t] = b;
    }
    __syncthreads();
    if (t < 64) {                              // csl[e] = sum_d kv_full[d][e]
        float s = 0.f;
        for (int d = 0; d < 64; ++d) s += kv[d * 68 + t];
        aux[(size_t)bh * 68 + t] = s + 64.0f * vsl[t];
    }
    if (t == 64) {                             // kstp = sum_d ksl[d]
        float s = 0.f;
        for (int d = 0; d < 64; ++d) s += kslL[d];
        aux[(size_t)bh * 68 + 64] = s;
    }
    __syncthreads();
    {   // rows 0..63: kvT[m][k] = kv[k][m] + vsl[m]
        int m = t >> 2, kq = t & 3;
        union { u16 h[16]; uint4 u[2]; } hh, ll;
        float vm = vsl[m];
#pragma unroll
        for (int i = 0; i < 16; ++i) {
            int k = kq * 16 + i;
            split2(kv[k * 68 + m] + vm, hh.h[i], ll.h[i]);
        }
        size_t off = (size_t)bh * 5120 + (size_t)m * 64 + kq * 16;
        *(uint4*)(kvTh + off) = hh.u[0];
        *(uint4*)(kvTh + off + 8) = hh.u[1];
        *(uint4*)(kvTl + off) = ll.u[0];
        *(uint4*)(kvTl + off + 8) = ll.u[1];
    }
    if (t < 64) {   // rows 64..79: 64=ksl, 65..79=0
        int m2 = 64 + (t >> 2), kq = t & 3;
        union { u16 h[16]; uint4 u[2]; } hh, ll;
#pragma unroll
        for (int i = 0; i < 16; ++i) {
            float v = (m2 == 64) ? kslL[kq * 16 + i] : 0.f;
            split2(v, hh.h[i], ll.h[i]);
        }
        size_t off = (size_t)bh * 5120 + (size_t)m2 * 64 + kq * 16;
        *(uint4*)(kvTh + off) = hh.u[0];
        *(uint4*)(kvTh + off + 8) = hh.u[1];
        *(uint4*)(kvTl + off) = ll.u[0];
        *(uint4*)(kvTl + off + 8) = ll.u[1];
    }
}

// ---- fused softmax-h + attention MFMA + gate. Block = (bh, 4-w columns).
// n' = w*64+h local index; global px n_g = h*64 + w0 + w.
__global__ __launch_bounds__(256) void k_smatt(
    const float* __restrict__ qf, const float* __restrict__ gf,
    const u16* __restrict__ kvTh_g, const u16* __restrict__ kvTl_g,
    const float* __restrict__ aux,
    u16* __restrict__ atth, u16* __restrict__ attl)
{
    __shared__ __align__(16) char smem[71680];
    float* qS   = (float*)smem;            // [256 n'][32 d] f32 per k-half (32KB)
    u16* fragH  = (u16*)(smem + 32768);    // [256][32] (16KB)
    u16* fragL  = (u16*)(smem + 49152);    // [256][32] (16KB)
    u16* ah_s   = (u16*)smem;              // reuse: att out [256][68]
    u16* al_s   = (u16*)(smem + 34816);
    float* szl  = (float*)(smem + 69632);  // [256]
    float* cslL = (float*)(smem + 70656);  // [65]
    const int t = threadIdx.x;
    const int lane = t & 63, wv = t >> 6;
    const int row = lane & 15, oct = lane >> 4;
    const int bh = blockIdx.y;
    const int bfl = bh >> 3, head = bh & 7;
    const int w0 = blockIdx.x * 4;

    if (t < 65) cslL[t] = aux[(size_t)bh * 68 + t];

    f32x4 acc[5][4] = {};
    const u16* Ahg = kvTh_g + (size_t)bh * 5120;
    const u16* Alg = kvTl_g + (size_t)bh * 5120;
    const float* qbase = qf + ((size_t)bfl * 4096) * 512 + head * 64;

    for (int ks = 0; ks < 2; ++ks) {
        // stage qS: 256 px x 32 f32 (128B/px, 8x16B lanes per px)
#pragma unroll
        for (int r = 0; r < 8; ++r) {
            int px = r * 32 + wv * 8 + (lane >> 3);
            int c  = lane & 7;
            int ng = (px & 63) * 64 + w0 + (px >> 6);
            gll16(qbase + (size_t)ng * 512 + ks * 32 + c * 4,
                  (char*)smem + r * 4096 + wv * 1024);
        }
        __syncthreads();
        if (t < 128) {                         // softmax over h per (w, d)
            int w = t >> 5, d = t & 31;
            const float* col = qS + (w * 64) * 32 + d;
            float mx = -3.0e38f;
            for (int h = 0; h < 64; ++h) mx = fmaxf(mx, col[h * 32]);
            float sum = 0.f;
            for (int h = 0; h < 64; ++h) sum += expf(col[h * 32] - mx);
            float rs = 1.0f / sum;
            for (int h = 0; h < 64; ++h) {
                float p = expf(col[h * 32] - mx) * rs;
                u16 hh, ll;
                split2(p, hh, ll);
                fragH[(w * 64 + h) * 32 + d] = hh;
                fragL[(w * 64 + h) * 32 + d] = ll;
            }
        }
        __syncthreads();
#pragma unroll
        for (int pass = 0; pass < 3; ++pass) { // 3-pass split on this k-half
            const u16* Ap = (pass == 2) ? Alg : Ahg;
            const u16* Bp = (pass == 1) ? fragL : fragH;
            bf16x8 af[5], bq[4];
#pragma unroll
            for (int mi = 0; mi < 5; ++mi)
                af[mi] = *(const bf16x8*)(Ap + (size_t)(mi * 16 + row) * 64 + ks * 32 + oct * 8);
#pragma unroll
            for (int ni = 0; ni < 4; ++ni)
                bq[ni] = *(const bf16x8*)(Bp + (wv * 64 + ni * 16 + row) * 32 + oct * 8);
#pragma unroll
            for (int mi = 0; mi < 5; ++mi)
#pragma unroll
                for (int ni = 0; ni < 4; ++ni)
                    acc[mi][ni] = __builtin_amdgcn_mfma_f32_16x16x32_bf16(af[mi], bq[ni], acc[mi][ni], 0, 0, 0);
        }
        __syncthreads();
    }
    if (oct == 0) {                            // row 64 of kvT_aug = ksl
#pragma unroll
        for (int ni = 0; ni < 4; ++ni)
            szl[wv * 64 + ni * 16 + row] = acc[4][ni][0];
    }
    __syncthreads();                           // frag/qS region now reusable

    const float kstp = cslL[64];
#pragma unroll
    for (int ni = 0; ni < 4; ++ni) {
        int n_loc = wv * 64 + ni * 16 + row;
        int n_g = (n_loc & 63) * 64 + w0 + (n_loc >> 6);
        float zz = 0.125f / fmaxf(szl[n_loc] + kstp, 1e-6f);
        const float* gp = gf + ((size_t)bfl * 4096 + n_g) * 512 + head * 64;
#pragma unroll
        for (int mi = 0; mi < 4; ++mi) {
            int e0 = mi * 16 + oct * 4;
            f32x4 g4 = *(const f32x4*)(gp + e0);
            u16 hh[4], ll2[4];
#pragma unroll
            for (int r2 = 0; r2 < 4; ++r2) {
                int e = e0 + r2;
                float val = (acc[mi][ni][r2] + cslL[e]) * zz * g4[r2];
                split2(val, hh[r2], ll2[r2]);
            }
            *(u32*)(ah_s + n_loc * 68 + e0)     = (u32)hh[0] | ((u32)hh[1] << 16);
            *(u32*)(ah_s + n_loc * 68 + e0 + 2) = (u32)hh[2] | ((u32)hh[3] << 16);
            *(u32*)(al_s + n_loc * 68 + e0)     = (u32)ll2[0] | ((u32)ll2[1] << 16);
            *(u32*)(al_s + n_loc * 68 + e0 + 2) = (u32)ll2[2] | ((u32)ll2[3] << 16);
        }
    }
    __syncthreads();
    u16* gh = atth + ((size_t)bfl * 4096) * 512 + head * 64;
    u16* gl = attl + ((size_t)bfl * 4096) * 512 + head * 64;
#pragma unroll
    for (int r = 0; r < 16; ++r) {
        int n_loc = r * 16 + (t >> 4);
        int u2 = t & 15;
        int n_g = (n_loc & 63) * 64 + w0 + (n_loc >> 6);
        *(uint2*)(gh + (size_t)n_g * 512 + u2 * 4) = *(const uint2*)(ah_s + n_loc * 68 + u2 * 4);
        *(uint2*)(gl + (size_t)n_g * 512 + u2 * 4) = *(const uint2*)(al_s + n_loc * 68 + u2 * 4);
    }
}

// --------------------------------- out = Wo x att + bo, f32, (b,c,f,h,w) layout
__global__ __launch_bounds__(256) void k_out(
    const u16* __restrict__ Woh, const u16* __restrict__ Wol,
    const u16* __restrict__ atth, const u16* __restrict__ attl,
    const float* __restrict__ bo, float* __restrict__ out, int c0)
{
    __shared__ __align__(16) u16 smem[32768];
    u16* Ah = smem;
    u16* Al = smem + 8192;
    u16* Bh = smem + 16384;
    u16* Bl = smem + 24576;
    const int t = threadIdx.x;
    const int bfl = blockIdx.z;
    const int bfg = c0 + bfl;
    const int m0 = blockIdx.y * 128;
    const int n0 = blockIdx.x * 128;
    const int lane = t & 63, wv = t >> 6, wm = wv >> 1, wn = wv & 1;
    f32x4 acc[4][4] = {};
    const u16* Aph = Woh + (size_t)m0 * 512;
    const u16* Apl = Wol + (size_t)m0 * 512;
    const u16* Bph = atth + ((size_t)bfl * 4096 + n0) * 512;
    const u16* Bpl = attl + ((size_t)bfl * 4096 + n0) * 512;
    for (int kt = 0; kt < 8; ++kt) {
        const int k0 = kt * 64;
#pragma unroll
        for (int jj = 0; jj < 4; ++jj) {
            int s = wv * 4 + jj;
            int row = s * 8 + (lane >> 3);
            int csrc = (lane & 7) ^ (row & 7);
            size_t go = (size_t)row * 512 + k0 + csrc * 8;
            gll16(Aph + go, Ah + s * 512);
            gll16(Apl + go, Al + s * 512);
            gll16(Bph + go, Bh + s * 512);
            gll16(Bpl + go, Bl + s * 512);
        }
        __syncthreads();
#pragma unroll
        for (int kk = 0; kk < 2; ++kk) {
            bf16x8 afh[4], afl[4], bfh[4], bfl_[4];
#pragma unroll
            for (int i = 0; i < 4; ++i) {
                int ra = wm * 64 + i * 16 + (lane & 15);
                int ca = ((kk * 4 + (lane >> 4)) ^ (ra & 7)) * 8;
                afh[i] = *(const bf16x8*)(Ah + ra * 64 + ca);
                afl[i] = *(const bf16x8*)(Al + ra * 64 + ca);
                int rb = wn * 64 + i * 16 + (lane & 15);
                int cb = ((kk * 4 + (lane >> 4)) ^ (rb & 7)) * 8;
                bfh[i] = *(const bf16x8*)(Bh + rb * 64 + cb);
                bfl_[i] = *(const bf16x8*)(Bl + rb * 64 + cb);
            }
#pragma unroll
            for (int mi = 0; mi < 4; ++mi)
#pragma unroll
                for (int ni = 0; ni < 4; ++ni) {
                    acc[mi][ni] = __builtin_amdgcn_mfma_f32_16x16x32_bf16(afh[mi], bfh[ni], acc[mi][ni], 0, 0, 0);
                    acc[mi][ni] = __builtin_amdgcn_mfma_f32_16x16x32_bf16(afh[mi], bfl_[ni], acc[mi][ni], 0, 0, 0);
                    acc[mi][ni] = __builtin_amdgcn_mfma_f32_16x16x32_bf16(afl[mi], bfh[ni], acc[mi][ni], 0, 0, 0);
                }
        }
        __syncthreads();
    }
    const int b_ = bfg >> 4, f_ = bfg & 15;
#pragma unroll
    for (int mi = 0; mi < 4; ++mi)
#pragma unroll
        for (int ni = 0; ni < 4; ++ni)
#pragma unroll
            for (int r = 0; r < 4; ++r) {
                int o = m0 + wm * 64 + mi * 16 + (lane >> 4) * 4 + r;
                int nn = n0 + wn * 64 + ni * 16 + (lane & 15);
                out[(((size_t)b_ * 256 + o) * 16 + f_) * 4096 + nn] = acc[mi][ni][r] + bo[o];
            }
}

extern "C" void kernel_launch(void* const* d_in, const int* in_sizes, int n_in,
                              void* d_out, int out_size, void* d_ws, size_t ws_size,
                              hipStream_t stream)
{
    const float* x  = (const float*)d_in[0];
    const float* Wq = (const float*)d_in[1];
    const float* Wk = (const float*)d_in[2];
    const float* Wv = (const float*)d_in[3];
    const float* Wg = (const float*)d_in[4];
    const float* bg = (const float*)d_in[5];
    const float* Wo = (const float*)d_in[6];
    const float* bo = (const float*)d_in[7];
    float* out = (float*)d_out;
    char* ws = (char*)d_ws;

    const size_t PER_BF = 38996096ull;
    const size_t FIXED  = 2621440ull;
    int CH = 32;
    while (CH > 1 && FIXED + (size_t)CH * PER_BF > ws_size) CH >>= 1;
    const int nch = 32 / CH;

    u16* Wh  = (u16*)(ws);
    u16* Wl  = (u16*)(ws + 1048576);
    u16* Woh = (u16*)(ws + 2097152);
    u16* Wol = (u16*)(ws + 2359296);
    char* dyn = ws + FIXED;
    u16*   xh   = (u16*)(dyn);
    u16*   xl   = (u16*)(dyn + (size_t)CH * 2097152);
    u16*   kh   = (u16*)(dyn + (size_t)CH * 4194304);    // att hi aliases after k_kv
    u16*   kl   = (u16*)(dyn + (size_t)CH * 8388608);    // att lo aliases after k_kv
    u16*   vh   = (u16*)(dyn + (size_t)CH * 12582912);
    u16*   vl   = (u16*)(dyn + (size_t)CH * 16777216);
    float* qf   = (float*)(dyn + (size_t)CH * 20971520);
    float* gf   = (float*)(dyn + (size_t)CH * 29360128);
    float* kvp  = (float*)(dyn + (size_t)CH * 37748736);
    float* vsp  = (float*)(dyn + (size_t)CH * 38797312);
    float* ksp  = (float*)(dyn + (size_t)CH * 38813696);
    u16*   kvTh = (u16*)(dyn + (size_t)CH * 38830080);
    u16*   kvTl = (u16*)(dyn + (size_t)CH * 38912000);
    float* aux  = (float*)(dyn + (size_t)CH * 38993920);
    u16*   atth = kh;
    u16*   attl = kl;

    k_cvt_w<<<dim3(2560), dim3(256), 0, stream>>>(Wq, Wk, Wv, Wg, Wo, Wh, Wl, Woh, Wol);

    for (int c = 0; c < nch; ++c) {
        const int c0 = c * CH;
        k_cvt_x<<<dim3(32, CH),     dim3(256), 0, stream>>>(x, xh, xl, c0);
        k_proj <<<dim3(32, 16, CH), dim3(256), 0, stream>>>(Wh, Wl, xh, xl, bg,
                                                            qf, kh, kl, vh, vl, gf);
        k_kv   <<<dim3(8, CH * 8),  dim3(256), 0, stream>>>(kh, kl, vh, vl, kvp, vsp, ksp);
        k_merge<<<dim3(CH * 8),     dim3(256), 0, stream>>>(kvp, vsp, ksp, kvTh, kvTl, aux, CH * 8);
        k_smatt<<<dim3(16, CH * 8), dim3(256), 0, stream>>>(qf, gf, kvTh, kvTl, aux, atth, attl);
        k_out  <<<dim3(32, 2, CH),  dim3(256), 0, stream>>>(Woh, Wol, atth, attl, bo, out, c0);
    }
}